// Round 5
// baseline (654.141 us; speedup 1.0000x reference)
//
#include <hip/hip_runtime.h>
#include <hip/hip_bf16.h>

#define NEGINF -1e30f

typedef __attribute__((ext_vector_type(8))) short short8;
typedef __attribute__((ext_vector_type(4))) float f32x4;

__device__ __forceinline__ float fast_tanh(float x) {
    float e = __expf(fminf(2.f * x, 80.f));
    return (e - 1.f) * __builtin_amdgcn_rcpf(e + 1.f);
}
__device__ __forceinline__ float fast_sigmoid(float x) {
    return __builtin_amdgcn_rcpf(1.f + __expf(fminf(-x, 80.f)));
}
// round-to-nearest-even f32 -> bf16 bits
__device__ __forceinline__ short f2bf(float f) {
    unsigned u = __float_as_uint(f);
    return (short)((u + 0x7fff + ((u >> 16) & 1)) >> 16);
}
__device__ __forceinline__ float bf2f(short b) {
    return __uint_as_float(((unsigned)(unsigned short)b) << 16);
}

// LDS-only workgroup barrier: waits lgkmcnt(0) but leaves vmcnt untouched.
__device__ __forceinline__ void bar_lds() {
    asm volatile("s_waitcnt lgkmcnt(0)\n\ts_barrier" ::: "memory");
}

// ---------------- Tiled f32 GEMM: out[M,N] = A[M,K] @ W[N,K]^T + bias ----------------
// Two weight/bias/out sets selectable by block tile (merges independent GEMMs sharing A).
// mode 0: plain bias. mode 1: out = sigmoid(acc+bias) * A[m, n]  (requires K == N)
__global__ __launch_bounds__(256) void gemm_bias(
    const float* __restrict__ A,
    const float* __restrict__ W1, const float* __restrict__ b1, float* __restrict__ out1,
    const float* __restrict__ W2, const float* __restrict__ b2, float* __restrict__ out2,
    int M, int N, int K, int nsplit, int mode) {
    __shared__ __align__(16) float At[16][64];
    __shared__ __align__(16) float Wt[16][64];
    const int tid = threadIdx.x;
    int bx = blockIdx.x;
    const float* W = W1; const float* bias = b1; float* out = out1;
    int n0;
    if (bx < nsplit) {
        n0 = bx * 64;
    } else {
        W = W2; bias = b2; out = out2;
        n0 = (bx - nsplit) * 64;
    }
    const int m0 = blockIdx.y * 64;
    const int tx = tid & 15;   // col group (4 cols)
    const int ty = tid >> 4;   // row group (4 rows)
    float acc[4][4];
#pragma unroll
    for (int r = 0; r < 4; r++)
#pragma unroll
        for (int c = 0; c < 4; c++) acc[r][c] = 0.f;

    const int lr = tid >> 2;          // 0..63 row within tile for loads
    const int lc = (tid & 3) * 4;     // 0..12 k within tile for loads

    for (int k0 = 0; k0 < K; k0 += 16) {
        float4 a = *(const float4*)(A + (size_t)(m0 + lr) * K + k0 + lc);
        float4 w = *(const float4*)(W + (size_t)(n0 + lr) * K + k0 + lc);
        At[lc + 0][lr] = a.x; At[lc + 1][lr] = a.y; At[lc + 2][lr] = a.z; At[lc + 3][lr] = a.w;
        Wt[lc + 0][lr] = w.x; Wt[lc + 1][lr] = w.y; Wt[lc + 2][lr] = w.z; Wt[lc + 3][lr] = w.w;
        __syncthreads();
#pragma unroll
        for (int kk = 0; kk < 16; kk++) {
            float4 av = *(const float4*)&At[kk][ty * 4];
            float4 wv = *(const float4*)&Wt[kk][tx * 4];
            const float* ap = (const float*)&av;
            const float* wp = (const float*)&wv;
#pragma unroll
            for (int r = 0; r < 4; r++)
#pragma unroll
                for (int c = 0; c < 4; c++) acc[r][c] += ap[r] * wp[c];
        }
        __syncthreads();
    }
    float4 bb = *(const float4*)(bias + n0 + tx * 4);
    const float* bp = (const float*)&bb;
#pragma unroll
    for (int r = 0; r < 4; r++) {
        int m = m0 + ty * 4 + r;
        float4 o;
        float* op = (float*)&o;
#pragma unroll
        for (int c = 0; c < 4; c++) op[c] = acc[r][c] + bp[c];
        if (mode == 1) {
            float4 av = *(const float4*)(A + (size_t)m * K + n0 + tx * 4);
            const float* ap = (const float*)&av;
#pragma unroll
            for (int c = 0; c < 4; c++) op[c] = fast_sigmoid(op[c]) * ap[c];
        }
        *(float4*)(out + (size_t)m * N + n0 + tx * 4) = o;
    }
}

// ---------------- Attention: scores(tanh-dot) -> masked softmax -> C = attn @ v ------
// Writes inp[b,q,:] = concat(v[b,q,:], C[b,q,:])   (inp is [B*L, 512])
__global__ __launch_bounds__(256) void attn_kernel(
    const float* __restrict__ v, const int* __restrict__ lengths,
    const float* __restrict__ own, const float* __restrict__ comp,
    const float* __restrict__ v_attn, float* __restrict__ inp) {
    const int L = 512, D = 256, H = 128;
    const int b = blockIdx.x >> 9;
    const int q = blockIdx.x & 511;
    const int tid = threadIdx.x;
    __shared__ float ownq[128];
    __shared__ float va[128];
    __shared__ float sc[512];
    __shared__ float red[256];
    if (tid < 128) {
        ownq[tid] = own[((size_t)(b * L + q)) * H + tid];
        va[tid] = v_attn[tid];
    }
    __syncthreads();
    const int len = lengths[b];
    float s2[2];
    float smax = NEGINF;
#pragma unroll
    for (int slot = 0; slot < 2; slot++) {
        int k = tid + slot * 256;
        float s = NEGINF;
        if (k < len) {
            const float* cp = comp + ((size_t)(b * L + k)) * H;
            s = 0.f;
#pragma unroll 4
            for (int h = 0; h < H; h += 4) {
                float4 c4 = *(const float4*)(cp + h);
                s += fast_tanh(ownq[h + 0] + c4.x) * va[h + 0];
                s += fast_tanh(ownq[h + 1] + c4.y) * va[h + 1];
                s += fast_tanh(ownq[h + 2] + c4.z) * va[h + 2];
                s += fast_tanh(ownq[h + 3] + c4.w) * va[h + 3];
            }
        }
        s2[slot] = s;
        smax = fmaxf(smax, s);
    }
    red[tid] = smax;
    __syncthreads();
    for (int off = 128; off > 0; off >>= 1) {
        if (tid < off) red[tid] = fmaxf(red[tid], red[tid + off]);
        __syncthreads();
    }
    float mx = red[0];
    __syncthreads();
    float lsum = 0.f;
#pragma unroll
    for (int slot = 0; slot < 2; slot++) {
        float e = __expf(s2[slot] - mx);
        sc[tid + slot * 256] = e;
        lsum += e;
    }
    red[tid] = lsum;
    __syncthreads();
    for (int off = 128; off > 0; off >>= 1) {
        if (tid < off) red[tid] += red[tid + off];
        __syncthreads();
    }
    float inv = __builtin_amdgcn_rcpf(red[0]);
    // context: thread tid owns output dim d = tid
    float a0 = 0.f, a1 = 0.f, a2 = 0.f, a3 = 0.f;
    const float* vb = v + ((size_t)b * L) * D + tid;
#pragma unroll 4
    for (int k = 0; k < L; k += 4) {
        a0 += sc[k + 0] * vb[(size_t)(k + 0) * D];
        a1 += sc[k + 1] * vb[(size_t)(k + 1) * D];
        a2 += sc[k + 2] * vb[(size_t)(k + 2) * D];
        a3 += sc[k + 3] * vb[(size_t)(k + 3) * D];
    }
    float accum = ((a0 + a1) + (a2 + a3)) * inv;
    size_t row = ((size_t)(b * L + q)) * 512;
    inp[row + 256 + tid] = accum;
    inp[row + tid] = v[((size_t)(b * L + q)) * D + tid];
}

// ---------------- Bidirectional GRU recurrence (MFMA matvec, hi/lo in B-columns) -----
// One block per (dir, batch), 768 threads = 12 waves; wave w owns rows 32w..32w+31.
// Per step: hp = W_hh @ h via mfma_f32_16x16x32_bf16 with B-col0 = h_hi, B-col1 = h_lo,
// A-combos {W_hi, W_lo}. Sum over {A-combos} x {cols 0,1} = (Whi+Wlo)(hhi+hlo) =
// full-precision product (error ~2^-17). Column merge via shfl_xor(1) (cols live in
// lanes mrow 0/1). Sum is symmetric in the two columns, so the result is independent
// of any hi/lo column permutation. 16 MFMA/wave/step (was 24).
__global__ __launch_bounds__(768, 3) void gru_kernel(
    const float* __restrict__ xp_f, const float* __restrict__ xp_b,
    const float* __restrict__ w_hh_f, const float* __restrict__ w_hh_b,
    const float* __restrict__ b_hh_f, const float* __restrict__ b_hh_b,
    const int* __restrict__ lengths, float* __restrict__ out) {
    const int L = 512, H = 128;
    const int dir = blockIdx.x >> 2;
    const int b = blockIdx.x & 3;
    const float* xp = dir ? xp_b : xp_f;
    const float* w_hh = dir ? w_hh_b : w_hh_f;
    const float* b_hh = dir ? b_hh_b : b_hh_f;
    const int tid = threadIdx.x;
    const int wave = tid >> 6;
    const int lane = tid & 63;
    const int mrow = lane & 15;  // A row within 16-row tile; also C column index
    const int quad = lane >> 4;  // k-quad

    __shared__ __align__(16) short hbuf[256];  // [0,128): h_hi bf16, [128,256): h_lo bf16
    __shared__ __align__(16) float hp[384];

    // ---- A-fragments: wave w owns rows 32w..32w+31 (tiles 2w, 2w+1), hi/lo split ----
    short8 whi[2][4], wlo[2][4];
#pragma unroll
    for (int mt = 0; mt < 2; mt++) {
        int row = 32 * wave + 16 * mt + mrow;
#pragma unroll
        for (int kt = 0; kt < 4; kt++) {
            const float* wp = w_hh + (size_t)row * H + kt * 32 + quad * 8;
            float4 w0 = *(const float4*)(wp);
            float4 w1 = *(const float4*)(wp + 4);
            float wv[8] = {w0.x, w0.y, w0.z, w0.w, w1.x, w1.y, w1.z, w1.w};
            short8 hi8, lo8;
#pragma unroll
            for (int jj = 0; jj < 8; jj++) {
                short hb = f2bf(wv[jj]);
                hi8[jj] = hb;
                lo8[jj] = f2bf(wv[jj] - bf2f(hb));
            }
            whi[mt][kt] = hi8;
            wlo[mt][kt] = lo8;
        }
    }
    // gate-thread biases
    float br = 0.f, bz = 0.f, bn = 0.f;
    if (tid < 128) {
        br = b_hh[tid];
        bz = b_hh[128 + tid];
        bn = b_hh[256 + tid];
    }

    const int len = lengths[b];
    // pre-zero masked tail
    for (int idx = tid; idx < (L - len) * 128; idx += 768) {
        int tt = len + (idx >> 7);
        int jj = idx & 127;
        out[((size_t)(b * L + tt)) * 256 + dir * 128 + jj] = 0.f;
    }
    if (tid < 256) hbuf[tid] = 0;
    float hcur = 0.f;
    __syncthreads();

    // preload xp for step 0 (gate threads)
    float xr = 0.f, xz = 0.f, xn = 0.f;
    if (tid < 128) {
        int t0 = dir ? (len - 1) : 0;
        size_t base = ((size_t)(b * L + t0)) * 384;
        xr = xp[base + tid];
        xz = xp[base + 128 + tid];
        xn = xp[base + 256 + tid];
    }

    // B-frag LDS index: column (mrow&1) selects hi/lo segment; lanes mrow>=2 load
    // duplicates whose C columns are never read.
    const int bbase = (mrow & 1) * 128 + quad * 8;

    for (int stp = 0; stp < len; stp++) {
        const int t = dir ? (len - 1 - stp) : stp;
        // prefetch next step's xp; stays in flight across bar_lds
        float nxr = 0.f, nxz = 0.f, nxn = 0.f;
        if (tid < 128 && (stp + 1 < len)) {
            int tn = dir ? (len - 2 - stp) : (stp + 1);
            size_t base = ((size_t)(b * L + tn)) * 384;
            nxr = xp[base + tid];
            nxz = xp[base + 128 + tid];
            nxn = xp[base + 256 + tid];
        }
        // B-fragments: one short8 per kt (broadcast-heavy, conflict-free)
        short8 bf[4];
#pragma unroll
        for (int kt = 0; kt < 4; kt++) bf[kt] = *(const short8*)&hbuf[bbase + kt * 32];

        f32x4 ahi[2], alo[2];
#pragma unroll
        for (int mt = 0; mt < 2; mt++) {
            ahi[mt] = (f32x4){0.f, 0.f, 0.f, 0.f};
            alo[mt] = (f32x4){0.f, 0.f, 0.f, 0.f};
        }
#pragma unroll
        for (int kt = 0; kt < 4; kt++) {
#pragma unroll
            for (int mt = 0; mt < 2; mt++) {
                ahi[mt] = __builtin_amdgcn_mfma_f32_16x16x32_bf16(whi[mt][kt], bf[kt], ahi[mt], 0, 0, 0);
                alo[mt] = __builtin_amdgcn_mfma_f32_16x16x32_bf16(wlo[mt][kt], bf[kt], alo[mt], 0, 0, 0);
            }
        }
        // merge A-combos in-lane, then merge the two B-columns across lane pair (mrow 0,1)
#pragma unroll
        for (int mt = 0; mt < 2; mt++) {
            f32x4 vsum = ahi[mt] + alo[mt];
            float v0 = vsum[0], v1 = vsum[1], v2 = vsum[2], v3 = vsum[3];
            v0 += __shfl_xor(v0, 1);
            v1 += __shfl_xor(v1, 1);
            v2 += __shfl_xor(v2, 1);
            v3 += __shfl_xor(v3, 1);
            if (mrow == 0) {  // C rows = quad*4 + reg
                f32x4 r = {v0, v1, v2, v3};
                *(f32x4*)&hp[32 * wave + 16 * mt + quad * 4] = r;
            }
        }
        bar_lds();  // hp ready; hbuf reads done
        float hn;
        if (tid < 128) {
            float hr = hp[tid] + br;
            float hz = hp[128 + tid] + bz;
            float hh = hp[256 + tid] + bn;
            float r = fast_sigmoid(xr + hr);
            float z = fast_sigmoid(xz + hz);
            float n = fast_tanh(xn + r * hh);
            hn = (1.f - z) * n + z * hcur;
            hcur = hn;
            short hb = f2bf(hn);
            hbuf[tid] = hb;
            hbuf[128 + tid] = f2bf(hn - bf2f(hb));
        }
        bar_lds();  // hbuf ready
        if (tid < 128) {
            out[((size_t)(b * L + t)) * 256 + dir * 128 + tid] = hn;  // fire-and-forget
            xr = nxr; xz = nxz; xn = nxn;
        }
    }
}

extern "C" void kernel_launch(void* const* d_in, const int* in_sizes, int n_in,
                              void* d_out, int out_size, void* d_ws, size_t ws_size,
                              hipStream_t stream) {
    const int B = 4, L = 512, D = 256, H = 128;
    const int M = B * L;  // 2048

    const float* v      = (const float*)d_in[0];
    const int* lengths  = (const int*)d_in[1];
    // d_in[2] = p_mask (bool) — unused, lengths is equivalent
    const float* own_W  = (const float*)d_in[3];
    const float* own_b  = (const float*)d_in[4];
    const float* comp_W = (const float*)d_in[5];
    const float* comp_b = (const float*)d_in[6];
    const float* v_attn = (const float*)d_in[7];
    const float* gate_W = (const float*)d_in[8];
    const float* gate_b = (const float*)d_in[9];
    const float* w_ih_f = (const float*)d_in[10];
    const float* w_hh_f = (const float*)d_in[11];
    const float* b_ih_f = (const float*)d_in[12];
    const float* b_hh_f = (const float*)d_in[13];
    const float* w_ih_b = (const float*)d_in[14];
    const float* w_hh_b = (const float*)d_in[15];
    const float* b_ih_b = (const float*)d_in[16];
    const float* b_hh_b = (const float*)d_in[17];

    float* ws   = (float*)d_ws;
    float* own  = ws;                       // [2048,128]
    float* comp = own + (size_t)M * H;      // [2048,128]
    float* inp  = comp + (size_t)M * H;     // [2048,512]
    float* gated = inp + (size_t)M * 512;   // [2048,512]
    float* xp_f = gated + (size_t)M * 512;  // [2048,384]
    float* xp_b = xp_f + (size_t)M * 384;   // [2048,384]
    float* out  = (float*)d_out;            // [2048,256]

    // 1: own & comp projections in one launch (tiles 0..1 -> own, 2..3 -> comp)
    gemm_bias<<<dim3(4, M / 64), 256, 0, stream>>>(
        v, own_W, own_b, own, comp_W, comp_b, comp, M, H, D, 2, 0);
    // 2: attention -> inp = [v, C]
    attn_kernel<<<dim3(B * L), 256, 0, stream>>>(v, lengths, own, comp, v_attn, inp);
    // 3: gate
    gemm_bias<<<dim3(8, M / 64), 256, 0, stream>>>(
        inp, gate_W, gate_b, gated, gate_W, gate_b, gated, M, 512, 512, 8, 1);
    // 4: input projections for both GRU directions in one launch
    gemm_bias<<<dim3(12, M / 64), 256, 0, stream>>>(
        gated, w_ih_f, b_ih_f, xp_f, w_ih_b, b_ih_b, xp_b, M, 384, 512, 6, 0);
    // 5: sequential GRU, one block per (dir, batch)
    gru_kernel<<<dim3(8), 768, 0, stream>>>(xp_f, xp_b, w_hh_f, w_hh_b, b_hh_f, b_hh_b, lengths, out);
}

// Round 6
// 578.163 us; speedup vs baseline: 1.1314x; 1.1314x over previous
//
#include <hip/hip_runtime.h>
#include <hip/hip_bf16.h>

#define NEGINF -1e30f

typedef __attribute__((ext_vector_type(8))) short short8;
typedef __attribute__((ext_vector_type(4))) float f32x4;

__device__ __forceinline__ float fast_tanh(float x) {
    float e = __expf(fminf(2.f * x, 80.f));
    return (e - 1.f) * __builtin_amdgcn_rcpf(e + 1.f);
}
__device__ __forceinline__ float fast_sigmoid(float x) {
    return __builtin_amdgcn_rcpf(1.f + __expf(fminf(-x, 80.f)));
}
// round-to-nearest-even f32 -> bf16 bits
__device__ __forceinline__ short f2bf(float f) {
    unsigned u = __float_as_uint(f);
    return (short)((u + 0x7fff + ((u >> 16) & 1)) >> 16);
}
__device__ __forceinline__ float bf2f(short b) {
    return __uint_as_float(((unsigned)(unsigned short)b) << 16);
}

// LDS-only workgroup barrier (correctness-proven in R3-R5). Even if the waitcnt
// pass conservatively drains vmcnt before the asm, the GRU step loop now has an
// empty vmem queue at every barrier (all global I/O happens at chunk boundaries).
__device__ __forceinline__ void bar_lds() {
    asm volatile("s_waitcnt lgkmcnt(0)\n\ts_barrier" ::: "memory");
}

// ---------------- Tiled f32 GEMM: out[M,N] = A[M,K] @ W[N,K]^T + bias ----------------
// Two weight/bias/out sets selectable by block tile (merges independent GEMMs sharing A).
// mode 0: plain bias. mode 1: out = sigmoid(acc+bias) * A[m, n]  (requires K == N)
__global__ __launch_bounds__(256) void gemm_bias(
    const float* __restrict__ A,
    const float* __restrict__ W1, const float* __restrict__ b1, float* __restrict__ out1,
    const float* __restrict__ W2, const float* __restrict__ b2, float* __restrict__ out2,
    int M, int N, int K, int nsplit, int mode) {
    __shared__ __align__(16) float At[16][64];
    __shared__ __align__(16) float Wt[16][64];
    const int tid = threadIdx.x;
    int bx = blockIdx.x;
    const float* W = W1; const float* bias = b1; float* out = out1;
    int n0;
    if (bx < nsplit) {
        n0 = bx * 64;
    } else {
        W = W2; bias = b2; out = out2;
        n0 = (bx - nsplit) * 64;
    }
    const int m0 = blockIdx.y * 64;
    const int tx = tid & 15;   // col group (4 cols)
    const int ty = tid >> 4;   // row group (4 rows)
    float acc[4][4];
#pragma unroll
    for (int r = 0; r < 4; r++)
#pragma unroll
        for (int c = 0; c < 4; c++) acc[r][c] = 0.f;

    const int lr = tid >> 2;          // 0..63 row within tile for loads
    const int lc = (tid & 3) * 4;     // 0..12 k within tile for loads

    for (int k0 = 0; k0 < K; k0 += 16) {
        float4 a = *(const float4*)(A + (size_t)(m0 + lr) * K + k0 + lc);
        float4 w = *(const float4*)(W + (size_t)(n0 + lr) * K + k0 + lc);
        At[lc + 0][lr] = a.x; At[lc + 1][lr] = a.y; At[lc + 2][lr] = a.z; At[lc + 3][lr] = a.w;
        Wt[lc + 0][lr] = w.x; Wt[lc + 1][lr] = w.y; Wt[lc + 2][lr] = w.z; Wt[lc + 3][lr] = w.w;
        __syncthreads();
#pragma unroll
        for (int kk = 0; kk < 16; kk++) {
            float4 av = *(const float4*)&At[kk][ty * 4];
            float4 wv = *(const float4*)&Wt[kk][tx * 4];
            const float* ap = (const float*)&av;
            const float* wp = (const float*)&wv;
#pragma unroll
            for (int r = 0; r < 4; r++)
#pragma unroll
                for (int c = 0; c < 4; c++) acc[r][c] += ap[r] * wp[c];
        }
        __syncthreads();
    }
    float4 bb = *(const float4*)(bias + n0 + tx * 4);
    const float* bp = (const float*)&bb;
#pragma unroll
    for (int r = 0; r < 4; r++) {
        int m = m0 + ty * 4 + r;
        float4 o;
        float* op = (float*)&o;
#pragma unroll
        for (int c = 0; c < 4; c++) op[c] = acc[r][c] + bp[c];
        if (mode == 1) {
            float4 av = *(const float4*)(A + (size_t)m * K + n0 + tx * 4);
            const float* ap = (const float*)&av;
#pragma unroll
            for (int c = 0; c < 4; c++) op[c] = fast_sigmoid(op[c]) * ap[c];
        }
        *(float4*)(out + (size_t)m * N + n0 + tx * 4) = o;
    }
}

// ---------------- Attention: scores(tanh-dot) -> masked softmax -> C = attn @ v ------
// Writes inp[b,q,:] = concat(v[b,q,:], C[b,q,:])   (inp is [B*L, 512])
__global__ __launch_bounds__(256) void attn_kernel(
    const float* __restrict__ v, const int* __restrict__ lengths,
    const float* __restrict__ own, const float* __restrict__ comp,
    const float* __restrict__ v_attn, float* __restrict__ inp) {
    const int L = 512, D = 256, H = 128;
    const int b = blockIdx.x >> 9;
    const int q = blockIdx.x & 511;
    const int tid = threadIdx.x;
    __shared__ float ownq[128];
    __shared__ float va[128];
    __shared__ float sc[512];
    __shared__ float red[256];
    if (tid < 128) {
        ownq[tid] = own[((size_t)(b * L + q)) * H + tid];
        va[tid] = v_attn[tid];
    }
    __syncthreads();
    const int len = lengths[b];
    float s2[2];
    float smax = NEGINF;
#pragma unroll
    for (int slot = 0; slot < 2; slot++) {
        int k = tid + slot * 256;
        float s = NEGINF;
        if (k < len) {
            const float* cp = comp + ((size_t)(b * L + k)) * H;
            s = 0.f;
#pragma unroll 4
            for (int h = 0; h < H; h += 4) {
                float4 c4 = *(const float4*)(cp + h);
                s += fast_tanh(ownq[h + 0] + c4.x) * va[h + 0];
                s += fast_tanh(ownq[h + 1] + c4.y) * va[h + 1];
                s += fast_tanh(ownq[h + 2] + c4.z) * va[h + 2];
                s += fast_tanh(ownq[h + 3] + c4.w) * va[h + 3];
            }
        }
        s2[slot] = s;
        smax = fmaxf(smax, s);
    }
    red[tid] = smax;
    __syncthreads();
    for (int off = 128; off > 0; off >>= 1) {
        if (tid < off) red[tid] = fmaxf(red[tid], red[tid + off]);
        __syncthreads();
    }
    float mx = red[0];
    __syncthreads();
    float lsum = 0.f;
#pragma unroll
    for (int slot = 0; slot < 2; slot++) {
        float e = __expf(s2[slot] - mx);
        sc[tid + slot * 256] = e;
        lsum += e;
    }
    red[tid] = lsum;
    __syncthreads();
    for (int off = 128; off > 0; off >>= 1) {
        if (tid < off) red[tid] += red[tid + off];
        __syncthreads();
    }
    float inv = __builtin_amdgcn_rcpf(red[0]);
    // context: thread tid owns output dim d = tid
    float a0 = 0.f, a1 = 0.f, a2 = 0.f, a3 = 0.f;
    const float* vb = v + ((size_t)b * L) * D + tid;
#pragma unroll 4
    for (int k = 0; k < L; k += 4) {
        a0 += sc[k + 0] * vb[(size_t)(k + 0) * D];
        a1 += sc[k + 1] * vb[(size_t)(k + 1) * D];
        a2 += sc[k + 2] * vb[(size_t)(k + 2) * D];
        a3 += sc[k + 3] * vb[(size_t)(k + 3) * D];
    }
    float accum = ((a0 + a1) + (a2 + a3)) * inv;
    size_t row = ((size_t)(b * L + q)) * 512;
    inp[row + 256 + tid] = accum;
    inp[row + tid] = v[((size_t)(b * L + q)) * D + tid];
}

// ---------------- Bidirectional GRU recurrence (MFMA + chunked LDS staging) ----------
// One block per (dir, batch), 768 threads = 12 waves. All global I/O happens at
// 16-step chunk boundaries: xp chunk (24 KB) is prefetched into registers one chunk
// ahead and committed to LDS at the chunk top; outputs accumulate in LDS obuf and
// flush once per chunk. Inside steps the vmem queue is empty -> barriers are cheap.
// Matvec: hp = W_hh @ h via mfma_f32_16x16x32_bf16, B-col0 = h_hi, B-col1 = h_lo,
// A in {W_hi, W_lo}; (Whi+Wlo)(hhi+hlo) = full product (error ~2^-17). Column merge
// via hp0/hp1 split writes (lanes mrow 0/1) + add in gate phase (no shfl).
__global__ __launch_bounds__(768, 3) void gru_kernel(
    const float* __restrict__ xp_f, const float* __restrict__ xp_b,
    const float* __restrict__ w_hh_f, const float* __restrict__ w_hh_b,
    const float* __restrict__ b_hh_f, const float* __restrict__ b_hh_b,
    const int* __restrict__ lengths, float* __restrict__ out) {
    const int L = 512, H = 128;
    const int dir = blockIdx.x >> 2;
    const int b = blockIdx.x & 3;
    const float* xp = dir ? xp_b : xp_f;
    const float* w_hh = dir ? w_hh_b : w_hh_f;
    const float* b_hh = dir ? b_hh_b : b_hh_f;
    const int tid = threadIdx.x;
    const int wave = tid >> 6;
    const int lane = tid & 63;
    const int mrow = lane & 15;  // A row within 16-row tile; C column index
    const int quad = lane >> 4;  // k-quad

    __shared__ __align__(16) short hbuf[256];   // [0,128) h_hi bf16, [128,256) h_lo
    __shared__ __align__(16) float hp0[384];    // B-col0 partial (W*h_hi)
    __shared__ __align__(16) float hp1[384];    // B-col1 partial (W*h_lo)
    __shared__ __align__(16) float xbuf[16 * 384];  // xp chunk stage (24 KB)
    __shared__ __align__(16) float obuf[16 * 128];  // output stage (8 KB)

    // ---- A-fragments: wave w owns rows 32w..32w+31 (tiles 2w, 2w+1), hi/lo split ----
    short8 whi[2][4], wlo[2][4];
#pragma unroll
    for (int mt = 0; mt < 2; mt++) {
        int row = 32 * wave + 16 * mt + mrow;
#pragma unroll
        for (int kt = 0; kt < 4; kt++) {
            const float* wp = w_hh + (size_t)row * H + kt * 32 + quad * 8;
            float4 w0 = *(const float4*)(wp);
            float4 w1 = *(const float4*)(wp + 4);
            float wv[8] = {w0.x, w0.y, w0.z, w0.w, w1.x, w1.y, w1.z, w1.w};
            short8 hi8, lo8;
#pragma unroll
            for (int jj = 0; jj < 8; jj++) {
                short hb = f2bf(wv[jj]);
                hi8[jj] = hb;
                lo8[jj] = f2bf(wv[jj] - bf2f(hb));
            }
            whi[mt][kt] = hi8;
            wlo[mt][kt] = lo8;
        }
    }
    // gate-thread biases
    float br = 0.f, bz = 0.f, bn = 0.f;
    if (tid < 128) {
        br = b_hh[tid];
        bz = b_hh[128 + tid];
        bn = b_hh[256 + tid];
    }

    const int len = lengths[b];
    // pre-zero masked tail: out[b, t, dir*128+jj] = 0 for t in [len, L)
    for (int idx = tid; idx < (L - len) * 128; idx += 768) {
        int tt = len + (idx >> 7);
        int jj = idx & 127;
        out[((size_t)(b * L + tt)) * 256 + dir * 128 + jj] = 0.f;
    }
    if (tid < 256) hbuf[tid] = 0;
    float hcur = 0.f;

    // staging geometry: thread handles float4 f0=tid (rows 0..7) and f1=tid+768 (rows 8..15)
    const int s0 = tid / 96;          // chunk-row for f0 (0..7); f1 row = s0+8
    const int j0 = (tid % 96) * 4;    // float offset within row

    const int nch = (len + 15) >> 4;  // len >= 256 so chunk 0 is always full
    // preamble: issue chunk-0 loads into registers
    float4 r0, r1;
    {
        int tA = dir ? (len - 1 - s0) : s0;
        int tB = dir ? (len - 1 - (s0 + 8)) : (s0 + 8);
        r0 = *(const float4*)&xp[((size_t)(b * L + tA)) * 384 + j0];
        r1 = *(const float4*)&xp[((size_t)(b * L + tB)) * 384 + j0];
    }
    __syncthreads();

    const int bbase = (mrow & 1) * 128 + quad * 8;  // B-frag hbuf index (col0=hi, col1=lo)

    for (int c = 0; c < nch; c++) {
        const int cnt = min(16, len - c * 16);
        // 1. commit staged registers to xbuf (vmcnt wait lands here, hidden by a full chunk)
        if (s0 < cnt) *(float4*)&xbuf[s0 * 384 + j0] = r0;
        if (s0 + 8 < cnt) *(float4*)&xbuf[(s0 + 8) * 384 + j0] = r1;
        // 2. flush previous chunk's outputs (full 16 rows; fire-and-forget stores)
        if (c > 0) {
            int p0 = (c - 1) * 16;
            for (int i = tid; i < 16 * 128; i += 768) {
                int ss = i >> 7, jj = i & 127;
                int tt = dir ? (len - 1 - (p0 + ss)) : (p0 + ss);
                out[((size_t)(b * L + tt)) * 256 + dir * 128 + jj] = obuf[i];
            }
        }
        // 3. prefetch chunk c+1 into registers (drains at most once per chunk)
        if (c + 1 < nch) {
            int ncnt = min(16, len - (c + 1) * 16);
            int sA = (c + 1) * 16 + s0, sB = sA + 8;
            if (s0 < ncnt) {
                int tt = dir ? (len - 1 - sA) : sA;
                r0 = *(const float4*)&xp[((size_t)(b * L + tt)) * 384 + j0];
            }
            if (s0 + 8 < ncnt) {
                int tt = dir ? (len - 1 - sB) : sB;
                r1 = *(const float4*)&xp[((size_t)(b * L + tt)) * 384 + j0];
            }
        }
        bar_lds();  // xbuf visible; flush obuf reads complete
        // 4. the 16 recurrence steps — zero global memory ops inside
        for (int s = 0; s < cnt; s++) {
            float xr, xz, xn;
            if (tid < 128) {
                xr = xbuf[s * 384 + tid];
                xz = xbuf[s * 384 + 128 + tid];
                xn = xbuf[s * 384 + 256 + tid];
            }
            short8 bf[4];
#pragma unroll
            for (int kt = 0; kt < 4; kt++) bf[kt] = *(const short8*)&hbuf[bbase + kt * 32];
            f32x4 ahi[2], alo[2];
#pragma unroll
            for (int mt = 0; mt < 2; mt++) {
                ahi[mt] = (f32x4){0.f, 0.f, 0.f, 0.f};
                alo[mt] = (f32x4){0.f, 0.f, 0.f, 0.f};
            }
#pragma unroll
            for (int kt = 0; kt < 4; kt++) {
#pragma unroll
                for (int mt = 0; mt < 2; mt++) {
                    ahi[mt] = __builtin_amdgcn_mfma_f32_16x16x32_bf16(whi[mt][kt], bf[kt], ahi[mt], 0, 0, 0);
                    alo[mt] = __builtin_amdgcn_mfma_f32_16x16x32_bf16(wlo[mt][kt], bf[kt], alo[mt], 0, 0, 0);
                }
            }
            if (mrow < 2) {  // C col (mrow) 0 holds W*h_hi, col 1 holds W*h_lo; rows = quad*4+reg
                float* hpx = (mrow == 0) ? hp0 : hp1;
                f32x4 v0 = ahi[0] + alo[0];
                f32x4 v1 = ahi[1] + alo[1];
                *(f32x4*)&hpx[32 * wave + quad * 4] = v0;
                *(f32x4*)&hpx[32 * wave + 16 + quad * 4] = v1;
            }
            bar_lds();  // hp ready; hbuf reads done
            if (tid < 128) {
                float hr = hp0[tid] + hp1[tid] + br;
                float hz = hp0[128 + tid] + hp1[128 + tid] + bz;
                float hh = hp0[256 + tid] + hp1[256 + tid] + bn;
                float r = fast_sigmoid(xr + hr);
                float z = fast_sigmoid(xz + hz);
                float n = fast_tanh(xn + r * hh);
                float hn = (1.f - z) * n + z * hcur;
                hcur = hn;
                short hb = f2bf(hn);
                hbuf[tid] = hb;
                hbuf[128 + tid] = f2bf(hn - bf2f(hb));
                obuf[s * 128 + tid] = hn;
            }
            bar_lds();  // hbuf/obuf ready
        }
    }
    // final flush (last chunk, possibly partial)
    {
        int p0 = (nch - 1) * 16;
        int pcnt = len - p0;
        for (int i = tid; i < pcnt * 128; i += 768) {
            int ss = i >> 7, jj = i & 127;
            int tt = dir ? (len - 1 - (p0 + ss)) : (p0 + ss);
            out[((size_t)(b * L + tt)) * 256 + dir * 128 + jj] = obuf[i];
        }
    }
}

extern "C" void kernel_launch(void* const* d_in, const int* in_sizes, int n_in,
                              void* d_out, int out_size, void* d_ws, size_t ws_size,
                              hipStream_t stream) {
    const int B = 4, L = 512, D = 256, H = 128;
    const int M = B * L;  // 2048

    const float* v      = (const float*)d_in[0];
    const int* lengths  = (const int*)d_in[1];
    // d_in[2] = p_mask (bool) — unused, lengths is equivalent
    const float* own_W  = (const float*)d_in[3];
    const float* own_b  = (const float*)d_in[4];
    const float* comp_W = (const float*)d_in[5];
    const float* comp_b = (const float*)d_in[6];
    const float* v_attn = (const float*)d_in[7];
    const float* gate_W = (const float*)d_in[8];
    const float* gate_b = (const float*)d_in[9];
    const float* w_ih_f = (const float*)d_in[10];
    const float* w_hh_f = (const float*)d_in[11];
    const float* b_ih_f = (const float*)d_in[12];
    const float* b_hh_f = (const float*)d_in[13];
    const float* w_ih_b = (const float*)d_in[14];
    const float* w_hh_b = (const float*)d_in[15];
    const float* b_ih_b = (const float*)d_in[16];
    const float* b_hh_b = (const float*)d_in[17];

    float* ws   = (float*)d_ws;
    float* own  = ws;                       // [2048,128]
    float* comp = own + (size_t)M * H;      // [2048,128]
    float* inp  = comp + (size_t)M * H;     // [2048,512]
    float* gated = inp + (size_t)M * 512;   // [2048,512]
    float* xp_f = gated + (size_t)M * 512;  // [2048,384]
    float* xp_b = xp_f + (size_t)M * 384;   // [2048,384]
    float* out  = (float*)d_out;            // [2048,256]

    // 1: own & comp projections in one launch (tiles 0..1 -> own, 2..3 -> comp)
    gemm_bias<<<dim3(4, M / 64), 256, 0, stream>>>(
        v, own_W, own_b, own, comp_W, comp_b, comp, M, H, D, 2, 0);
    // 2: attention -> inp = [v, C]
    attn_kernel<<<dim3(B * L), 256, 0, stream>>>(v, lengths, own, comp, v_attn, inp);
    // 3: gate
    gemm_bias<<<dim3(8, M / 64), 256, 0, stream>>>(
        inp, gate_W, gate_b, gated, gate_W, gate_b, gated, M, 512, 512, 8, 1);
    // 4: input projections for both GRU directions in one launch
    gemm_bias<<<dim3(12, M / 64), 256, 0, stream>>>(
        gated, w_ih_f, b_ih_f, xp_f, w_ih_b, b_ih_b, xp_b, M, 384, 512, 6, 0);
    // 5: sequential GRU, one block per (dir, batch)
    gru_kernel<<<dim3(8), 768, 0, stream>>>(xp_f, xp_b, w_hh_f, w_hh_b, b_hh_f, b_hh_b, lengths, out);
}

// Round 7
// 529.215 us; speedup vs baseline: 1.2361x; 1.0925x over previous
//
#include <hip/hip_runtime.h>
#include <hip/hip_bf16.h>

#define NEGINF -1e30f

typedef __attribute__((ext_vector_type(8))) short short8;
typedef __attribute__((ext_vector_type(4))) float f32x4;

__device__ __forceinline__ float fast_tanh(float x) {
    float e = __expf(fminf(2.f * x, 80.f));
    return (e - 1.f) * __builtin_amdgcn_rcpf(e + 1.f);
}
__device__ __forceinline__ float fast_sigmoid(float x) {
    return __builtin_amdgcn_rcpf(1.f + __expf(fminf(-x, 80.f)));
}
// round-to-nearest-even f32 -> bf16 bits
__device__ __forceinline__ short f2bf(float f) {
    unsigned u = __float_as_uint(f);
    return (short)((u + 0x7fff + ((u >> 16) & 1)) >> 16);
}
__device__ __forceinline__ float bf2f(short b) {
    return __uint_as_float(((unsigned)(unsigned short)b) << 16);
}

// LDS-only workgroup barrier (proven R3-R6).
__device__ __forceinline__ void bar_lds() {
    asm volatile("s_waitcnt lgkmcnt(0)\n\ts_barrier" ::: "memory");
}
// same-wave LDS write->read fence (no barrier): DS ops are in-order per wave;
// lgkmcnt(0) guarantees the writes have landed before dependent reads issue.
__device__ __forceinline__ void fence_lds() {
    asm volatile("s_waitcnt lgkmcnt(0)" ::: "memory");
}

// ---------------- Tiled f32 GEMM: out[M,N] = A[M,K] @ W[N,K]^T + bias ----------------
// Two weight/bias/out sets selectable by block tile (merges independent GEMMs sharing A).
// mode 0: plain bias. mode 1: out = sigmoid(acc+bias) * A[m, n]  (requires K == N)
__global__ __launch_bounds__(256) void gemm_bias(
    const float* __restrict__ A,
    const float* __restrict__ W1, const float* __restrict__ b1, float* __restrict__ out1,
    const float* __restrict__ W2, const float* __restrict__ b2, float* __restrict__ out2,
    int M, int N, int K, int nsplit, int mode) {
    __shared__ __align__(16) float At[16][64];
    __shared__ __align__(16) float Wt[16][64];
    const int tid = threadIdx.x;
    int bx = blockIdx.x;
    const float* W = W1; const float* bias = b1; float* out = out1;
    int n0;
    if (bx < nsplit) {
        n0 = bx * 64;
    } else {
        W = W2; bias = b2; out = out2;
        n0 = (bx - nsplit) * 64;
    }
    const int m0 = blockIdx.y * 64;
    const int tx = tid & 15;   // col group (4 cols)
    const int ty = tid >> 4;   // row group (4 rows)
    float acc[4][4];
#pragma unroll
    for (int r = 0; r < 4; r++)
#pragma unroll
        for (int c = 0; c < 4; c++) acc[r][c] = 0.f;

    const int lr = tid >> 2;          // 0..63 row within tile for loads
    const int lc = (tid & 3) * 4;     // 0..12 k within tile for loads

    for (int k0 = 0; k0 < K; k0 += 16) {
        float4 a = *(const float4*)(A + (size_t)(m0 + lr) * K + k0 + lc);
        float4 w = *(const float4*)(W + (size_t)(n0 + lr) * K + k0 + lc);
        At[lc + 0][lr] = a.x; At[lc + 1][lr] = a.y; At[lc + 2][lr] = a.z; At[lc + 3][lr] = a.w;
        Wt[lc + 0][lr] = w.x; Wt[lc + 1][lr] = w.y; Wt[lc + 2][lr] = w.z; Wt[lc + 3][lr] = w.w;
        __syncthreads();
#pragma unroll
        for (int kk = 0; kk < 16; kk++) {
            float4 av = *(const float4*)&At[kk][ty * 4];
            float4 wv = *(const float4*)&Wt[kk][tx * 4];
            const float* ap = (const float*)&av;
            const float* wp = (const float*)&wv;
#pragma unroll
            for (int r = 0; r < 4; r++)
#pragma unroll
                for (int c = 0; c < 4; c++) acc[r][c] += ap[r] * wp[c];
        }
        __syncthreads();
    }
    float4 bb = *(const float4*)(bias + n0 + tx * 4);
    const float* bp = (const float*)&bb;
#pragma unroll
    for (int r = 0; r < 4; r++) {
        int m = m0 + ty * 4 + r;
        float4 o;
        float* op = (float*)&o;
#pragma unroll
        for (int c = 0; c < 4; c++) op[c] = acc[r][c] + bp[c];
        if (mode == 1) {
            float4 av = *(const float4*)(A + (size_t)m * K + n0 + tx * 4);
            const float* ap = (const float*)&av;
#pragma unroll
            for (int c = 0; c < 4; c++) op[c] = fast_sigmoid(op[c]) * ap[c];
        }
        *(float4*)(out + (size_t)m * N + n0 + tx * 4) = o;
    }
}

// ---------------- Attention: scores(tanh-dot) -> masked softmax -> C = attn @ v ------
// Writes inp[b,q,:] = concat(v[b,q,:], C[b,q,:])   (inp is [B*L, 512])
__global__ __launch_bounds__(256) void attn_kernel(
    const float* __restrict__ v, const int* __restrict__ lengths,
    const float* __restrict__ own, const float* __restrict__ comp,
    const float* __restrict__ v_attn, float* __restrict__ inp) {
    const int L = 512, D = 256, H = 128;
    const int b = blockIdx.x >> 9;
    const int q = blockIdx.x & 511;
    const int tid = threadIdx.x;
    __shared__ float ownq[128];
    __shared__ float va[128];
    __shared__ float sc[512];
    __shared__ float red[256];
    if (tid < 128) {
        ownq[tid] = own[((size_t)(b * L + q)) * H + tid];
        va[tid] = v_attn[tid];
    }
    __syncthreads();
    const int len = lengths[b];
    float s2[2];
    float smax = NEGINF;
#pragma unroll
    for (int slot = 0; slot < 2; slot++) {
        int k = tid + slot * 256;
        float s = NEGINF;
        if (k < len) {
            const float* cp = comp + ((size_t)(b * L + k)) * H;
            s = 0.f;
#pragma unroll 4
            for (int h = 0; h < H; h += 4) {
                float4 c4 = *(const float4*)(cp + h);
                s += fast_tanh(ownq[h + 0] + c4.x) * va[h + 0];
                s += fast_tanh(ownq[h + 1] + c4.y) * va[h + 1];
                s += fast_tanh(ownq[h + 2] + c4.z) * va[h + 2];
                s += fast_tanh(ownq[h + 3] + c4.w) * va[h + 3];
            }
        }
        s2[slot] = s;
        smax = fmaxf(smax, s);
    }
    red[tid] = smax;
    __syncthreads();
    for (int off = 128; off > 0; off >>= 1) {
        if (tid < off) red[tid] = fmaxf(red[tid], red[tid + off]);
        __syncthreads();
    }
    float mx = red[0];
    __syncthreads();
    float lsum = 0.f;
#pragma unroll
    for (int slot = 0; slot < 2; slot++) {
        float e = __expf(s2[slot] - mx);
        sc[tid + slot * 256] = e;
        lsum += e;
    }
    red[tid] = lsum;
    __syncthreads();
    for (int off = 128; off > 0; off >>= 1) {
        if (tid < off) red[tid] += red[tid + off];
        __syncthreads();
    }
    float inv = __builtin_amdgcn_rcpf(red[0]);
    // context: thread tid owns output dim d = tid
    float a0 = 0.f, a1 = 0.f, a2 = 0.f, a3 = 0.f;
    const float* vb = v + ((size_t)b * L) * D + tid;
#pragma unroll 4
    for (int k = 0; k < L; k += 4) {
        a0 += sc[k + 0] * vb[(size_t)(k + 0) * D];
        a1 += sc[k + 1] * vb[(size_t)(k + 1) * D];
        a2 += sc[k + 2] * vb[(size_t)(k + 2) * D];
        a3 += sc[k + 3] * vb[(size_t)(k + 3) * D];
    }
    float accum = ((a0 + a1) + (a2 + a3)) * inv;
    size_t row = ((size_t)(b * L + q)) * 512;
    inp[row + 256 + tid] = accum;
    inp[row + tid] = v[((size_t)(b * L + q)) * D + tid];
}

// ---------------- Bidirectional GRU recurrence (single-barrier MFMA) ----------------
// One block per (dir, batch), 512 threads = 8 waves. Wave w owns gate dims
// jj = 16w..16w+15: its 3 MFMA M-tiles are W_hh rows {g*128 + 16w + m}, g in {r,z,n},
// so the hp triplets land wave-locally -> transpose via per-wave LDS scratch
// (same-wave, fence_lds only, NO barrier). Gates run on lanes 0..15 of every wave
// (spread over all SIMDs). h round-trips through parity-double-buffered hbuf with
// ONE bar_lds per step. A = bf16(W) only (W_lo dropped: error ~3e-3 « 1.5e-2 thr);
// B cols {h_hi, h_lo} so h stays f32-exact: hp = bf16(W) . h. Chunked global I/O
// (xbuf/obuf) as R6 — zero global ops inside steps.
__global__ __launch_bounds__(512, 2) void gru_kernel(
    const float* __restrict__ xp_f, const float* __restrict__ xp_b,
    const float* __restrict__ w_hh_f, const float* __restrict__ w_hh_b,
    const float* __restrict__ b_hh_f, const float* __restrict__ b_hh_b,
    const int* __restrict__ lengths, float* __restrict__ out) {
    const int L = 512, H = 128;
    const int dir = blockIdx.x >> 2;
    const int b = blockIdx.x & 3;
    const float* xp = dir ? xp_b : xp_f;
    const float* w_hh = dir ? w_hh_b : w_hh_f;
    const float* b_hh = dir ? b_hh_b : b_hh_f;
    const int tid = threadIdx.x;
    const int wave = tid >> 6;
    const int lane = tid & 63;
    const int mrow = lane & 15;  // A row within 16-row tile; C column index
    const int quad = lane >> 4;  // k-quad
    const int jj = 16 * wave + lane;  // gate dim for lanes lane<16

    __shared__ __align__(16) short hbuf[2][256];       // [parity][hi 0..127 | lo 128..255]
    __shared__ __align__(16) float hpw[8][2][3][16];   // [wave][col][gate][m] scratch
    __shared__ __align__(16) float xbuf[16 * 384];     // xp chunk stage (24 KB)
    __shared__ __align__(16) float obuf[16 * 128];     // output stage (8 KB)

    // ---- A-fragments: wave w, tile g = gate, rows = g*128 + 16w + mrow ----
    short8 wa[3][4];
#pragma unroll
    for (int g = 0; g < 3; g++) {
        int row = g * 128 + 16 * wave + mrow;
#pragma unroll
        for (int kt = 0; kt < 4; kt++) {
            const float* wp = w_hh + (size_t)row * H + kt * 32 + quad * 8;
            float4 w0 = *(const float4*)(wp);
            float4 w1 = *(const float4*)(wp + 4);
            float wv[8] = {w0.x, w0.y, w0.z, w0.w, w1.x, w1.y, w1.z, w1.w};
            short8 hi8;
#pragma unroll
            for (int k = 0; k < 8; k++) hi8[k] = f2bf(wv[k]);
            wa[g][kt] = hi8;
        }
    }
    float br = 0.f, bz = 0.f, bn = 0.f, hcur = 0.f;
    if (lane < 16) {
        br = b_hh[jj];
        bz = b_hh[128 + jj];
        bn = b_hh[256 + jj];
    }

    const int len = lengths[b];
    // pre-zero masked tail: out[b, t, dir*128+k] = 0 for t in [len, L)
    for (int idx = tid; idx < (L - len) * 128; idx += 512) {
        int tt = len + (idx >> 7);
        int kk = idx & 127;
        out[((size_t)(b * L + tt)) * 256 + dir * 128 + kk] = 0.f;
    }
    if (tid < 256) hbuf[0][tid] = 0;

    // staging geometry: 1536 float4 per chunk, 3 per thread
    const int f1 = tid + 512, f2 = tid + 1024;
    const int sA = tid / 96, jA = (tid % 96) * 4;
    const int sB = f1 / 96, jB = (f1 % 96) * 4;
    const int sC = f2 / 96, jC = (f2 % 96) * 4;

    const int nch = (len + 15) >> 4;  // len >= 256 so chunk 0 is full
    float4 r0, r1, r2;
    {
        int tA = dir ? (len - 1 - sA) : sA;
        int tB = dir ? (len - 1 - sB) : sB;
        int tC = dir ? (len - 1 - sC) : sC;
        r0 = *(const float4*)&xp[((size_t)(b * L + tA)) * 384 + jA];
        r1 = *(const float4*)&xp[((size_t)(b * L + tB)) * 384 + jB];
        r2 = *(const float4*)&xp[((size_t)(b * L + tC)) * 384 + jC];
    }
    __syncthreads();

    const int bbase = (mrow & 1) * 128 + quad * 8;  // B-frag index: col0=hi, col1=lo
    int par = 0;

    for (int c = 0; c < nch; c++) {
        const int cnt = min(16, len - c * 16);
        // commit staged regs (vmcnt wait lands here, hidden by a full chunk)
        if (sA < cnt) *(float4*)&xbuf[sA * 384 + jA] = r0;
        if (sB < cnt) *(float4*)&xbuf[sB * 384 + jB] = r1;
        if (sC < cnt) *(float4*)&xbuf[sC * 384 + jC] = r2;
        // flush previous chunk's outputs (always a full 16 rows)
        if (c > 0) {
            int p0 = (c - 1) * 16;
            for (int i = tid; i < 16 * 128; i += 512) {
                int ss = i >> 7, kk = i & 127;
                int tt = dir ? (len - 1 - (p0 + ss)) : (p0 + ss);
                out[((size_t)(b * L + tt)) * 256 + dir * 128 + kk] = obuf[i];
            }
        }
        // prefetch chunk c+1 into registers
        if (c + 1 < nch) {
            int ncnt = min(16, len - (c + 1) * 16);
            int base = (c + 1) * 16;
            if (sA < ncnt) {
                int tt = dir ? (len - 1 - (base + sA)) : (base + sA);
                r0 = *(const float4*)&xp[((size_t)(b * L + tt)) * 384 + jA];
            }
            if (sB < ncnt) {
                int tt = dir ? (len - 1 - (base + sB)) : (base + sB);
                r1 = *(const float4*)&xp[((size_t)(b * L + tt)) * 384 + jB];
            }
            if (sC < ncnt) {
                int tt = dir ? (len - 1 - (base + sC)) : (base + sC);
                r2 = *(const float4*)&xp[((size_t)(b * L + tt)) * 384 + jC];
            }
        }
        bar_lds();  // xbuf visible; prev obuf reads complete
        for (int s = 0; s < cnt; s++) {
            // gate-input LDS reads issued early (latency hidden under MFMA)
            float xr, xz, xn;
            if (lane < 16) {
                xr = xbuf[s * 384 + jj];
                xz = xbuf[s * 384 + 128 + jj];
                xn = xbuf[s * 384 + 256 + jj];
            }
            short8 bf[4];
#pragma unroll
            for (int kt = 0; kt < 4; kt++) bf[kt] = *(const short8*)&hbuf[par][bbase + kt * 32];
            f32x4 acc[3];
#pragma unroll
            for (int g = 0; g < 3; g++) acc[g] = (f32x4){0.f, 0.f, 0.f, 0.f};
#pragma unroll
            for (int kt = 0; kt < 4; kt++)
#pragma unroll
                for (int g = 0; g < 3; g++)
                    acc[g] = __builtin_amdgcn_mfma_f32_16x16x32_bf16(wa[g][kt], bf[kt], acc[g], 0, 0, 0);
            // C cols 0/1 (lanes mrow 0/1) hold W*h_hi / W*h_lo; rows = quad*4+reg.
            // Park both in per-wave scratch; gate lanes sum them (no cross-wave traffic).
            if (mrow < 2) {
#pragma unroll
                for (int g = 0; g < 3; g++)
                    *(f32x4*)&hpw[wave][mrow][g][quad * 4] = acc[g];
            }
            fence_lds();  // same-wave write->read ordering, no barrier
            if (lane < 16) {
                float hr = hpw[wave][0][0][lane] + hpw[wave][1][0][lane] + br;
                float hz = hpw[wave][0][1][lane] + hpw[wave][1][1][lane] + bz;
                float hh = hpw[wave][0][2][lane] + hpw[wave][1][2][lane] + bn;
                float r = fast_sigmoid(xr + hr);
                float z = fast_sigmoid(xz + hz);
                float n = fast_tanh(xn + r * hh);
                float hn = (1.f - z) * n + z * hcur;
                hcur = hn;
                short hb = f2bf(hn);
                hbuf[par ^ 1][jj] = hb;
                hbuf[par ^ 1][128 + jj] = f2bf(hn - bf2f(hb));
                obuf[s * 128 + jj] = hn;
            }
            par ^= 1;
            bar_lds();  // hbuf[par] ready for all waves; single barrier per step
        }
    }
    // final flush (last chunk, possibly partial)
    {
        int p0 = (nch - 1) * 16;
        int pcnt = len - p0;
        for (int i = tid; i < pcnt * 128; i += 512) {
            int ss = i >> 7, kk = i & 127;
            int tt = dir ? (len - 1 - (p0 + ss)) : (p0 + ss);
            out[((size_t)(b * L + tt)) * 256 + dir * 128 + kk] = obuf[i];
        }
    }
}

extern "C" void kernel_launch(void* const* d_in, const int* in_sizes, int n_in,
                              void* d_out, int out_size, void* d_ws, size_t ws_size,
                              hipStream_t stream) {
    const int B = 4, L = 512, D = 256, H = 128;
    const int M = B * L;  // 2048

    const float* v      = (const float*)d_in[0];
    const int* lengths  = (const int*)d_in[1];
    // d_in[2] = p_mask (bool) — unused, lengths is equivalent
    const float* own_W  = (const float*)d_in[3];
    const float* own_b  = (const float*)d_in[4];
    const float* comp_W = (const float*)d_in[5];
    const float* comp_b = (const float*)d_in[6];
    const float* v_attn = (const float*)d_in[7];
    const float* gate_W = (const float*)d_in[8];
    const float* gate_b = (const float*)d_in[9];
    const float* w_ih_f = (const float*)d_in[10];
    const float* w_hh_f = (const float*)d_in[11];
    const float* b_ih_f = (const float*)d_in[12];
    const float* b_hh_f = (const float*)d_in[13];
    const float* w_ih_b = (const float*)d_in[14];
    const float* w_hh_b = (const float*)d_in[15];
    const float* b_ih_b = (const float*)d_in[16];
    const float* b_hh_b = (const float*)d_in[17];

    float* ws   = (float*)d_ws;
    float* own  = ws;                       // [2048,128]
    float* comp = own + (size_t)M * H;      // [2048,128]
    float* inp  = comp + (size_t)M * H;     // [2048,512]
    float* gated = inp + (size_t)M * 512;   // [2048,512]
    float* xp_f = gated + (size_t)M * 512;  // [2048,384]
    float* xp_b = xp_f + (size_t)M * 384;   // [2048,384]
    float* out  = (float*)d_out;            // [2048,256]

    // 1: own & comp projections in one launch (tiles 0..1 -> own, 2..3 -> comp)
    gemm_bias<<<dim3(4, M / 64), 256, 0, stream>>>(
        v, own_W, own_b, own, comp_W, comp_b, comp, M, H, D, 2, 0);
    // 2: attention -> inp = [v, C]
    attn_kernel<<<dim3(B * L), 256, 0, stream>>>(v, lengths, own, comp, v_attn, inp);
    // 3: gate
    gemm_bias<<<dim3(8, M / 64), 256, 0, stream>>>(
        inp, gate_W, gate_b, gated, gate_W, gate_b, gated, M, 512, 512, 8, 1);
    // 4: input projections for both GRU directions in one launch
    gemm_bias<<<dim3(12, M / 64), 256, 0, stream>>>(
        gated, w_ih_f, b_ih_f, xp_f, w_ih_b, b_ih_b, xp_b, M, 384, 512, 6, 0);
    // 5: sequential GRU, one block per (dir, batch)
    gru_kernel<<<dim3(8), 512, 0, stream>>>(xp_f, xp_b, w_hh_f, w_hh_b, b_hh_f, b_hh_b, lengths, out);
}

// Round 8
// 455.961 us; speedup vs baseline: 1.4346x; 1.1607x over previous
//
#include <hip/hip_runtime.h>
#include <hip/hip_bf16.h>

#define NEGINF -1e30f

typedef __attribute__((ext_vector_type(8))) short short8;
typedef __attribute__((ext_vector_type(4))) float f32x4;

__device__ __forceinline__ float fast_tanh(float x) {
    float e = __expf(fminf(2.f * x, 80.f));
    return (e - 1.f) * __builtin_amdgcn_rcpf(e + 1.f);
}
__device__ __forceinline__ float fast_sigmoid(float x) {
    return __builtin_amdgcn_rcpf(1.f + __expf(fminf(-x, 80.f)));
}
// round-to-nearest-even f32 -> bf16 bits
__device__ __forceinline__ short f2bf(float f) {
    unsigned u = __float_as_uint(f);
    return (short)((u + 0x7fff + ((u >> 16) & 1)) >> 16);
}
__device__ __forceinline__ float bf2f(short b) {
    return __uint_as_float(((unsigned)(unsigned short)b) << 16);
}

// LDS-only workgroup barrier (proven R3-R7): waits lgkmcnt only; in-flight global
// loads (same-thread register dests) and fire-and-forget stores are NOT drained.
// Safe when all cross-thread traffic goes through LDS.
__device__ __forceinline__ void bar_lds() {
    asm volatile("s_waitcnt lgkmcnt(0)\n\ts_barrier" ::: "memory");
}

// ---------------- Tiled f32 GEMM (pipelined): out[M,N] = A[M,K] @ W[N,K]^T + bias ----
// Register-prefetch + parity LDS buffers + single LDS-only barrier per k-iter:
// global loads for tile k+1 stay in flight across the barrier (R6 recipe).
// Two weight/bias/out sets selectable by block tile. mode 1: out = sigmoid(.)*A.
__global__ __launch_bounds__(256) void gemm_bias(
    const float* __restrict__ A,
    const float* __restrict__ W1, const float* __restrict__ b1, float* __restrict__ out1,
    const float* __restrict__ W2, const float* __restrict__ b2, float* __restrict__ out2,
    int M, int N, int K, int nsplit, int mode) {
    __shared__ __align__(16) float At[2][16][64];
    __shared__ __align__(16) float Wt[2][16][64];
    const int tid = threadIdx.x;
    int bx = blockIdx.x;
    const float* W = W1; const float* bias = b1; float* out = out1;
    int n0;
    if (bx < nsplit) {
        n0 = bx * 64;
    } else {
        W = W2; bias = b2; out = out2;
        n0 = (bx - nsplit) * 64;
    }
    const int m0 = blockIdx.y * 64;
    const int tx = tid & 15;   // col group (4 cols)
    const int ty = tid >> 4;   // row group (4 rows)
    float acc[4][4];
#pragma unroll
    for (int r = 0; r < 4; r++)
#pragma unroll
        for (int c = 0; c < 4; c++) acc[r][c] = 0.f;

    const int lr = tid >> 2;          // 0..63 row within tile for loads
    const int lc = (tid & 3) * 4;     // k within tile for loads

    // preload k-tile 0
    float4 a = *(const float4*)(A + (size_t)(m0 + lr) * K + lc);
    float4 w = *(const float4*)(W + (size_t)(n0 + lr) * K + lc);

    for (int k0 = 0; k0 < K; k0 += 16) {
        const int cur = (k0 >> 4) & 1;
        // commit staged regs (vmcnt wait lands here; load had a full iter in flight)
        At[cur][lc + 0][lr] = a.x; At[cur][lc + 1][lr] = a.y;
        At[cur][lc + 2][lr] = a.z; At[cur][lc + 3][lr] = a.w;
        Wt[cur][lc + 0][lr] = w.x; Wt[cur][lc + 1][lr] = w.y;
        Wt[cur][lc + 2][lr] = w.z; Wt[cur][lc + 3][lr] = w.w;
        // prefetch k-tile k0+16 (stays in flight across bar_lds)
        if (k0 + 16 < K) {
            a = *(const float4*)(A + (size_t)(m0 + lr) * K + k0 + 16 + lc);
            w = *(const float4*)(W + (size_t)(n0 + lr) * K + k0 + 16 + lc);
        }
        bar_lds();  // single barrier per iter: parity buffer prevents WAR
#pragma unroll
        for (int kk = 0; kk < 16; kk++) {
            float4 av = *(const float4*)&At[cur][kk][ty * 4];
            float4 wv = *(const float4*)&Wt[cur][kk][tx * 4];
            const float* ap = (const float*)&av;
            const float* wp = (const float*)&wv;
#pragma unroll
            for (int r = 0; r < 4; r++)
#pragma unroll
                for (int c = 0; c < 4; c++) acc[r][c] += ap[r] * wp[c];
        }
    }
    float4 bb = *(const float4*)(bias + n0 + tx * 4);
    const float* bp = (const float*)&bb;
#pragma unroll
    for (int r = 0; r < 4; r++) {
        int m = m0 + ty * 4 + r;
        float4 o;
        float* op = (float*)&o;
#pragma unroll
        for (int c = 0; c < 4; c++) op[c] = acc[r][c] + bp[c];
        if (mode == 1) {
            float4 av = *(const float4*)(A + (size_t)m * K + n0 + tx * 4);
            const float* ap = (const float*)&av;
#pragma unroll
            for (int c = 0; c < 4; c++) op[c] = fast_sigmoid(op[c]) * ap[c];
        }
        *(float4*)(out + (size_t)m * N + n0 + tx * 4) = o;
    }
}

// ---------------- Attention: scores(tanh-dot) -> masked softmax -> C = attn @ v ------
// Writes inp[b,q,:] = concat(v[b,q,:], C[b,q,:])   (inp is [B*L, 512])
__global__ __launch_bounds__(256) void attn_kernel(
    const float* __restrict__ v, const int* __restrict__ lengths,
    const float* __restrict__ own, const float* __restrict__ comp,
    const float* __restrict__ v_attn, float* __restrict__ inp) {
    const int L = 512, D = 256, H = 128;
    const int b = blockIdx.x >> 9;
    const int q = blockIdx.x & 511;
    const int tid = threadIdx.x;
    __shared__ float ownq[128];
    __shared__ float va[128];
    __shared__ float sc[512];
    __shared__ float red[256];
    if (tid < 128) {
        ownq[tid] = own[((size_t)(b * L + q)) * H + tid];
        va[tid] = v_attn[tid];
    }
    __syncthreads();
    const int len = lengths[b];
    float s2[2];
    float smax = NEGINF;
#pragma unroll
    for (int slot = 0; slot < 2; slot++) {
        int k = tid + slot * 256;
        float s = NEGINF;
        if (k < len) {
            const float* cp = comp + ((size_t)(b * L + k)) * H;
            s = 0.f;
#pragma unroll 4
            for (int h = 0; h < H; h += 4) {
                float4 c4 = *(const float4*)(cp + h);
                s += fast_tanh(ownq[h + 0] + c4.x) * va[h + 0];
                s += fast_tanh(ownq[h + 1] + c4.y) * va[h + 1];
                s += fast_tanh(ownq[h + 2] + c4.z) * va[h + 2];
                s += fast_tanh(ownq[h + 3] + c4.w) * va[h + 3];
            }
        }
        s2[slot] = s;
        smax = fmaxf(smax, s);
    }
    red[tid] = smax;
    __syncthreads();
    for (int off = 128; off > 0; off >>= 1) {
        if (tid < off) red[tid] = fmaxf(red[tid], red[tid + off]);
        __syncthreads();
    }
    float mx = red[0];
    __syncthreads();
    float lsum = 0.f;
#pragma unroll
    for (int slot = 0; slot < 2; slot++) {
        float e = __expf(s2[slot] - mx);
        sc[tid + slot * 256] = e;
        lsum += e;
    }
    red[tid] = lsum;
    __syncthreads();
    for (int off = 128; off > 0; off >>= 1) {
        if (tid < off) red[tid] += red[tid + off];
        __syncthreads();
    }
    float inv = __builtin_amdgcn_rcpf(red[0]);
    // context: thread tid owns output dim d = tid
    float a0 = 0.f, a1 = 0.f, a2 = 0.f, a3 = 0.f;
    const float* vb = v + ((size_t)b * L) * D + tid;
#pragma unroll 4
    for (int k = 0; k < L; k += 4) {
        a0 += sc[k + 0] * vb[(size_t)(k + 0) * D];
        a1 += sc[k + 1] * vb[(size_t)(k + 1) * D];
        a2 += sc[k + 2] * vb[(size_t)(k + 2) * D];
        a3 += sc[k + 3] * vb[(size_t)(k + 3) * D];
    }
    float accum = ((a0 + a1) + (a2 + a3)) * inv;
    size_t row = ((size_t)(b * L + q)) * 512;
    inp[row + 256 + tid] = accum;
    inp[row + tid] = v[((size_t)(b * L + q)) * D + tid];
}

// ---------------- Bidirectional GRU recurrence (operand-swapped MFMA) ---------------
// One block per (dir, batch), 512 threads = 8 waves. Wave w owns gate dims
// jj = 16w..16w+15. OPERAND SWAP vs R7: h is the A operand (row0 = h_hi, row1 = h_lo,
// rows 2-15 harmless duplicates via bbase mask), W^T is the B operand (B[k][n]:
// n = lane&15 -> gate dim 16w+n; same register data as R7's wa, reinterpreted).
// C[0][c] = W.h_hi and C[1][c] = W.h_lo land at col c = lane (lanes 0-15), regs 0/1 —
// the hp triplet arrives directly in the gate lane's own acc registers. No hpw
// scratch, no fence: per step = MFMA -> gate ALU -> hbuf write -> ONE bar_lds.
// A = bf16(W) (R7 scheme, absmax 0.0039 verified); h stays f32-exact via hi/lo cols.
// Chunked global I/O (xbuf/obuf) as R6 — zero global ops inside steps.
__global__ __launch_bounds__(512, 2) void gru_kernel(
    const float* __restrict__ xp_f, const float* __restrict__ xp_b,
    const float* __restrict__ w_hh_f, const float* __restrict__ w_hh_b,
    const float* __restrict__ b_hh_f, const float* __restrict__ b_hh_b,
    const int* __restrict__ lengths, float* __restrict__ out) {
    const int L = 512, H = 128;
    const int dir = blockIdx.x >> 2;
    const int b = blockIdx.x & 3;
    const float* xp = dir ? xp_b : xp_f;
    const float* w_hh = dir ? w_hh_b : w_hh_f;
    const float* b_hh = dir ? b_hh_b : b_hh_f;
    const int tid = threadIdx.x;
    const int wave = tid >> 6;
    const int lane = tid & 63;
    const int mrow = lane & 15;  // n index of B (gate dim within tile); A row index
    const int quad = lane >> 4;  // k-quad
    const int jj = 16 * wave + lane;  // gate dim for lanes lane<16

    __shared__ __align__(16) short hbuf[2][256];   // [parity][hi 0..127 | lo 128..255]
    __shared__ __align__(16) float xbuf[16 * 384]; // xp chunk stage (24 KB)
    __shared__ __align__(16) float obuf[16 * 128]; // output stage (8 KB)

    // ---- B-fragments (weights): wave w, gate g, B[k][n] = W_hh[g*128+16w+n][k];
    // lane (mrow, quad) loads W_hh[g*128+16w+mrow][kt*32 + quad*8 .. +8] ----
    short8 wb[3][4];
#pragma unroll
    for (int g = 0; g < 3; g++) {
        int row = g * 128 + 16 * wave + mrow;
#pragma unroll
        for (int kt = 0; kt < 4; kt++) {
            const float* wp = w_hh + (size_t)row * H + kt * 32 + quad * 8;
            float4 w0 = *(const float4*)(wp);
            float4 w1 = *(const float4*)(wp + 4);
            float wv[8] = {w0.x, w0.y, w0.z, w0.w, w1.x, w1.y, w1.z, w1.w};
            short8 hi8;
#pragma unroll
            for (int k = 0; k < 8; k++) hi8[k] = f2bf(wv[k]);
            wb[g][kt] = hi8;
        }
    }
    float br = 0.f, bz = 0.f, bn = 0.f, hcur = 0.f;
    if (lane < 16) {
        br = b_hh[jj];
        bz = b_hh[128 + jj];
        bn = b_hh[256 + jj];
    }

    const int len = lengths[b];
    // pre-zero masked tail: out[b, t, dir*128+k] = 0 for t in [len, L)
    for (int idx = tid; idx < (L - len) * 128; idx += 512) {
        int tt = len + (idx >> 7);
        int kk = idx & 127;
        out[((size_t)(b * L + tt)) * 256 + dir * 128 + kk] = 0.f;
    }
    if (tid < 256) hbuf[0][tid] = 0;

    // staging geometry: 1536 float4 per chunk, 3 per thread
    const int f1 = tid + 512, f2 = tid + 1024;
    const int sA = tid / 96, jA = (tid % 96) * 4;
    const int sB = f1 / 96, jB = (f1 % 96) * 4;
    const int sC = f2 / 96, jC = (f2 % 96) * 4;

    const int nch = (len + 15) >> 4;  // len >= 256 so chunk 0 is full
    float4 r0, r1, r2;
    {
        int tA = dir ? (len - 1 - sA) : sA;
        int tB = dir ? (len - 1 - sB) : sB;
        int tC = dir ? (len - 1 - sC) : sC;
        r0 = *(const float4*)&xp[((size_t)(b * L + tA)) * 384 + jA];
        r1 = *(const float4*)&xp[((size_t)(b * L + tB)) * 384 + jB];
        r2 = *(const float4*)&xp[((size_t)(b * L + tC)) * 384 + jC];
    }
    __syncthreads();

    const int bbase = (mrow & 1) * 128 + quad * 8;  // A-frag index: row0=hi, row1=lo
    int par = 0;

    for (int c = 0; c < nch; c++) {
        const int cnt = min(16, len - c * 16);
        // commit staged regs (vmcnt wait lands here, hidden by a full chunk)
        if (sA < cnt) *(float4*)&xbuf[sA * 384 + jA] = r0;
        if (sB < cnt) *(float4*)&xbuf[sB * 384 + jB] = r1;
        if (sC < cnt) *(float4*)&xbuf[sC * 384 + jC] = r2;
        // flush previous chunk's outputs (always a full 16 rows)
        if (c > 0) {
            int p0 = (c - 1) * 16;
            for (int i = tid; i < 16 * 128; i += 512) {
                int ss = i >> 7, kk = i & 127;
                int tt = dir ? (len - 1 - (p0 + ss)) : (p0 + ss);
                out[((size_t)(b * L + tt)) * 256 + dir * 128 + kk] = obuf[i];
            }
        }
        // prefetch chunk c+1 into registers
        if (c + 1 < nch) {
            int ncnt = min(16, len - (c + 1) * 16);
            int base = (c + 1) * 16;
            if (sA < ncnt) {
                int tt = dir ? (len - 1 - (base + sA)) : (base + sA);
                r0 = *(const float4*)&xp[((size_t)(b * L + tt)) * 384 + jA];
            }
            if (sB < ncnt) {
                int tt = dir ? (len - 1 - (base + sB)) : (base + sB);
                r1 = *(const float4*)&xp[((size_t)(b * L + tt)) * 384 + jB];
            }
            if (sC < ncnt) {
                int tt = dir ? (len - 1 - (base + sC)) : (base + sC);
                r2 = *(const float4*)&xp[((size_t)(b * L + tt)) * 384 + jC];
            }
        }
        bar_lds();  // xbuf visible; prev obuf reads complete
        for (int s = 0; s < cnt; s++) {
            // gate-input LDS reads issued early (latency hidden under MFMA)
            float xr, xz, xn;
            if (lane < 16) {
                xr = xbuf[s * 384 + jj];
                xz = xbuf[s * 384 + 128 + jj];
                xn = xbuf[s * 384 + 256 + jj];
            }
            // A-fragments: rows 0/1 = h_hi/h_lo (rows 2-15 duplicates, ignored in C)
            short8 af[4];
#pragma unroll
            for (int kt = 0; kt < 4; kt++) af[kt] = *(const short8*)&hbuf[par][bbase + kt * 32];
            f32x4 acc[3];
#pragma unroll
            for (int g = 0; g < 3; g++) acc[g] = (f32x4){0.f, 0.f, 0.f, 0.f};
#pragma unroll
            for (int kt = 0; kt < 4; kt++)
#pragma unroll
                for (int g = 0; g < 3; g++)
                    acc[g] = __builtin_amdgcn_mfma_f32_16x16x32_bf16(af[kt], wb[g][kt], acc[g], 0, 0, 0);
            // C col = lane (lanes 0-15 = this wave's gate dims); regs 0/1 = rows 0/1
            // = W.h_hi / W.h_lo. hp arrives in-register — no LDS transpose.
            if (lane < 16) {
                float hr = acc[0][0] + acc[0][1] + br;
                float hz = acc[1][0] + acc[1][1] + bz;
                float hh = acc[2][0] + acc[2][1] + bn;
                float r = fast_sigmoid(xr + hr);
                float z = fast_sigmoid(xz + hz);
                float n = fast_tanh(xn + r * hh);
                float hn = (1.f - z) * n + z * hcur;
                hcur = hn;
                short hb = f2bf(hn);
                hbuf[par ^ 1][jj] = hb;
                hbuf[par ^ 1][128 + jj] = f2bf(hn - bf2f(hb));
                obuf[s * 128 + jj] = hn;
            }
            par ^= 1;
            bar_lds();  // hbuf[par] ready for all waves; single barrier per step
        }
    }
    // final flush (last chunk, possibly partial)
    {
        int p0 = (nch - 1) * 16;
        int pcnt = len - p0;
        for (int i = tid; i < pcnt * 128; i += 512) {
            int ss = i >> 7, kk = i & 127;
            int tt = dir ? (len - 1 - (p0 + ss)) : (p0 + ss);
            out[((size_t)(b * L + tt)) * 256 + dir * 128 + kk] = obuf[i];
        }
    }
}

extern "C" void kernel_launch(void* const* d_in, const int* in_sizes, int n_in,
                              void* d_out, int out_size, void* d_ws, size_t ws_size,
                              hipStream_t stream) {
    const int B = 4, L = 512, D = 256, H = 128;
    const int M = B * L;  // 2048

    const float* v      = (const float*)d_in[0];
    const int* lengths  = (const int*)d_in[1];
    // d_in[2] = p_mask (bool) — unused, lengths is equivalent
    const float* own_W  = (const float*)d_in[3];
    const float* own_b  = (const float*)d_in[4];
    const float* comp_W = (const float*)d_in[5];
    const float* comp_b = (const float*)d_in[6];
    const float* v_attn = (const float*)d_in[7];
    const float* gate_W = (const float*)d_in[8];
    const float* gate_b = (const float*)d_in[9];
    const float* w_ih_f = (const float*)d_in[10];
    const float* w_hh_f = (const float*)d_in[11];
    const float* b_ih_f = (const float*)d_in[12];
    const float* b_hh_f = (const float*)d_in[13];
    const float* w_ih_b = (const float*)d_in[14];
    const float* w_hh_b = (const float*)d_in[15];
    const float* b_ih_b = (const float*)d_in[16];
    const float* b_hh_b = (const float*)d_in[17];

    float* ws   = (float*)d_ws;
    float* own  = ws;                       // [2048,128]
    float* comp = own + (size_t)M * H;      // [2048,128]
    float* inp  = comp + (size_t)M * H;     // [2048,512]
    float* gated = inp + (size_t)M * 512;   // [2048,512]
    float* xp_f = gated + (size_t)M * 512;  // [2048,384]
    float* xp_b = xp_f + (size_t)M * 384;   // [2048,384]
    float* out  = (float*)d_out;            // [2048,256]

    // 1: own & comp projections in one launch (tiles 0..1 -> own, 2..3 -> comp)
    gemm_bias<<<dim3(4, M / 64), 256, 0, stream>>>(
        v, own_W, own_b, own, comp_W, comp_b, comp, M, H, D, 2, 0);
    // 2: attention -> inp = [v, C]
    attn_kernel<<<dim3(B * L), 256, 0, stream>>>(v, lengths, own, comp, v_attn, inp);
    // 3: gate
    gemm_bias<<<dim3(8, M / 64), 256, 0, stream>>>(
        inp, gate_W, gate_b, gated, gate_W, gate_b, gated, M, 512, 512, 8, 1);
    // 4: input projections for both GRU directions in one launch
    gemm_bias<<<dim3(12, M / 64), 256, 0, stream>>>(
        gated, w_ih_f, b_ih_f, xp_f, w_ih_b, b_ih_b, xp_b, M, 384, 512, 6, 0);
    // 5: sequential GRU, one block per (dir, batch)
    gru_kernel<<<dim3(8), 512, 0, stream>>>(xp_f, xp_b, w_hh_f, w_hh_b, b_hh_f, b_hh_b, lengths, out);
}

// Round 9
// 441.269 us; speedup vs baseline: 1.4824x; 1.0333x over previous
//
#include <hip/hip_runtime.h>
#include <hip/hip_bf16.h>

#define NEGINF -1e30f

typedef __attribute__((ext_vector_type(8))) short short8;
typedef __attribute__((ext_vector_type(4))) float f32x4;

// Clamp-free: IEEE inf semantics give exact limits (exp->inf => rcp->0), NaN-free.
__device__ __forceinline__ float fast_sigmoid(float x) {
    return __builtin_amdgcn_rcpf(1.f + __expf(-x));
}
__device__ __forceinline__ float fast_tanh(float x) {
    // tanh(x) = 1 - 2/(1+e^{2x}); x->+inf: 1-0=1, x->-inf: 1-2=-1
    return 1.f - 2.f * __builtin_amdgcn_rcpf(1.f + __expf(2.f * x));
}
// round-to-nearest-even f32 -> bf16 bits
__device__ __forceinline__ short f2bf(float f) {
    unsigned u = __float_as_uint(f);
    return (short)((u + 0x7fff + ((u >> 16) & 1)) >> 16);
}
__device__ __forceinline__ float bf2f(short b) {
    return __uint_as_float(((unsigned)(unsigned short)b) << 16);
}

// LDS-only workgroup barrier (proven R3-R8): waits lgkmcnt only; in-flight global
// loads/stores are NOT drained. Safe when all cross-thread traffic goes through LDS.
__device__ __forceinline__ void bar_lds() {
    asm volatile("s_waitcnt lgkmcnt(0)\n\ts_barrier" ::: "memory");
}

// ---------------- Tiled f32 GEMM (pipelined): out[M,N] = A[M,K] @ W[N,K]^T + bias ----
// Register-prefetch + parity LDS buffers + single LDS-only barrier per k-iter.
// Row-tiles entirely past lengths[batch] are skipped (outputs unread downstream).
// Two weight/bias/out sets selectable by block tile. mode 1: out = sigmoid(.)*A.
__global__ __launch_bounds__(256) void gemm_bias(
    const float* __restrict__ A,
    const float* __restrict__ W1, const float* __restrict__ b1, float* __restrict__ out1,
    const float* __restrict__ W2, const float* __restrict__ b2, float* __restrict__ out2,
    const int* __restrict__ lengths,
    int M, int N, int K, int nsplit, int mode) {
    const int m0 = blockIdx.y * 64;
    if ((m0 & 511) >= lengths[m0 >> 9]) return;  // uniform per block; rows unread
    __shared__ __align__(16) float At[2][16][64];
    __shared__ __align__(16) float Wt[2][16][64];
    const int tid = threadIdx.x;
    int bx = blockIdx.x;
    const float* W = W1; const float* bias = b1; float* out = out1;
    int n0;
    if (bx < nsplit) {
        n0 = bx * 64;
    } else {
        W = W2; bias = b2; out = out2;
        n0 = (bx - nsplit) * 64;
    }
    const int tx = tid & 15;   // col group (4 cols)
    const int ty = tid >> 4;   // row group (4 rows)
    float acc[4][4];
#pragma unroll
    for (int r = 0; r < 4; r++)
#pragma unroll
        for (int c = 0; c < 4; c++) acc[r][c] = 0.f;

    const int lr = tid >> 2;          // 0..63 row within tile for loads
    const int lc = (tid & 3) * 4;     // k within tile for loads

    // preload k-tile 0
    float4 a = *(const float4*)(A + (size_t)(m0 + lr) * K + lc);
    float4 w = *(const float4*)(W + (size_t)(n0 + lr) * K + lc);

    for (int k0 = 0; k0 < K; k0 += 16) {
        const int cur = (k0 >> 4) & 1;
        // commit staged regs (vmcnt wait lands here; load had a full iter in flight)
        At[cur][lc + 0][lr] = a.x; At[cur][lc + 1][lr] = a.y;
        At[cur][lc + 2][lr] = a.z; At[cur][lc + 3][lr] = a.w;
        Wt[cur][lc + 0][lr] = w.x; Wt[cur][lc + 1][lr] = w.y;
        Wt[cur][lc + 2][lr] = w.z; Wt[cur][lc + 3][lr] = w.w;
        // prefetch k-tile k0+16 (stays in flight across bar_lds)
        if (k0 + 16 < K) {
            a = *(const float4*)(A + (size_t)(m0 + lr) * K + k0 + 16 + lc);
            w = *(const float4*)(W + (size_t)(n0 + lr) * K + k0 + 16 + lc);
        }
        bar_lds();  // single barrier per iter: parity buffer prevents WAR
#pragma unroll
        for (int kk = 0; kk < 16; kk++) {
            float4 av = *(const float4*)&At[cur][kk][ty * 4];
            float4 wv = *(const float4*)&Wt[cur][kk][tx * 4];
            const float* ap = (const float*)&av;
            const float* wp = (const float*)&wv;
#pragma unroll
            for (int r = 0; r < 4; r++)
#pragma unroll
                for (int c = 0; c < 4; c++) acc[r][c] += ap[r] * wp[c];
        }
    }
    float4 bb = *(const float4*)(bias + n0 + tx * 4);
    const float* bp = (const float*)&bb;
#pragma unroll
    for (int r = 0; r < 4; r++) {
        int m = m0 + ty * 4 + r;
        float4 o;
        float* op = (float*)&o;
#pragma unroll
        for (int c = 0; c < 4; c++) op[c] = acc[r][c] + bp[c];
        if (mode == 1) {
            float4 av = *(const float4*)(A + (size_t)m * K + n0 + tx * 4);
            const float* ap = (const float*)&av;
#pragma unroll
            for (int c = 0; c < 4; c++) op[c] = fast_sigmoid(op[c]) * ap[c];
        }
        *(float4*)(out + (size_t)m * N + n0 + tx * 4) = o;
    }
}

// ---------------- Attention: scores(tanh-dot) -> masked softmax -> C = attn @ v ------
// score(q,k) = sum_h va_h * tanh(o_h + c_h) = VA_SUM + sum_h va2_h * r_h where
// r = 1/(1+exp(2(o+c))), va2 = -2*va, and the 2*log2e scale is folded into oK.
// Inner body: fma, exp, add, rcp, fma (was ~10 insts). Blocks with q >= len exit.
// Writes inp[b,q,:] = concat(v[b,q,:], C[b,q,:])   (inp is [B*L, 512])
__global__ __launch_bounds__(256) void attn_kernel(
    const float* __restrict__ v, const int* __restrict__ lengths,
    const float* __restrict__ own, const float* __restrict__ comp,
    const float* __restrict__ v_attn, float* __restrict__ inp) {
    const int L = 512, D = 256, H = 128;
    const int b = blockIdx.x >> 9;
    const int q = blockIdx.x & 511;
    const int len = lengths[b];
    if (q >= len) return;  // uniform per block; inp rows >= len unread downstream
    const int tid = threadIdx.x;
    const float K2E = 2.8853900817779268f;  // 2*log2(e): exp(2x) = exp2(K2E*x)
    __shared__ float oK[128];    // K2E * own_q
    __shared__ float va2[128];   // -2 * v_attn
    __shared__ float sc[512];
    __shared__ float red[256];
    if (tid < 128) {
        oK[tid] = K2E * own[((size_t)(b * L + q)) * H + tid];
        va2[tid] = -2.f * v_attn[tid];
    }
    // VA_SUM = sum(v_attn) = -0.5 * sum(va2)
    red[tid] = (tid < 128) ? v_attn[tid] : 0.f;
    __syncthreads();
    for (int off = 128; off > 0; off >>= 1) {
        if (tid < off) red[tid] += red[tid + off];
        __syncthreads();
    }
    const float VA_SUM = red[0];
    __syncthreads();
    float s2[2];
    float smax = NEGINF;
#pragma unroll
    for (int slot = 0; slot < 2; slot++) {
        int k = tid + slot * 256;
        float s = NEGINF;
        if (k < len) {
            const float* cp = comp + ((size_t)(b * L + k)) * H;
            float acc = VA_SUM;
#pragma unroll 4
            for (int h = 0; h < H; h += 4) {
                float4 c4 = *(const float4*)(cp + h);
                // r = 1/(1+exp2(K2E*c + oK)); acc += va2*r
                float r0 = __builtin_amdgcn_rcpf(1.f + exp2f(fmaf(c4.x, K2E, oK[h + 0])));
                float r1 = __builtin_amdgcn_rcpf(1.f + exp2f(fmaf(c4.y, K2E, oK[h + 1])));
                float r2 = __builtin_amdgcn_rcpf(1.f + exp2f(fmaf(c4.z, K2E, oK[h + 2])));
                float r3 = __builtin_amdgcn_rcpf(1.f + exp2f(fmaf(c4.w, K2E, oK[h + 3])));
                acc = fmaf(va2[h + 0], r0, acc);
                acc = fmaf(va2[h + 1], r1, acc);
                acc = fmaf(va2[h + 2], r2, acc);
                acc = fmaf(va2[h + 3], r3, acc);
            }
            s = acc;
        }
        s2[slot] = s;
        smax = fmaxf(smax, s);
    }
    red[tid] = smax;
    __syncthreads();
    for (int off = 128; off > 0; off >>= 1) {
        if (tid < off) red[tid] = fmaxf(red[tid], red[tid + off]);
        __syncthreads();
    }
    float mx = red[0];
    __syncthreads();
    float lsum = 0.f;
#pragma unroll
    for (int slot = 0; slot < 2; slot++) {
        float e = __expf(s2[slot] - mx);
        sc[tid + slot * 256] = e;
        lsum += e;
    }
    red[tid] = lsum;
    __syncthreads();
    for (int off = 128; off > 0; off >>= 1) {
        if (tid < off) red[tid] += red[tid + off];
        __syncthreads();
    }
    float inv = __builtin_amdgcn_rcpf(red[0]);
    // context: thread tid owns output dim d = tid
    float a0 = 0.f, a1 = 0.f, a2 = 0.f, a3 = 0.f;
    const float* vb = v + ((size_t)b * L) * D + tid;
#pragma unroll 4
    for (int k = 0; k < L; k += 4) {
        a0 += sc[k + 0] * vb[(size_t)(k + 0) * D];
        a1 += sc[k + 1] * vb[(size_t)(k + 1) * D];
        a2 += sc[k + 2] * vb[(size_t)(k + 2) * D];
        a3 += sc[k + 3] * vb[(size_t)(k + 3) * D];
    }
    float accum = ((a0 + a1) + (a2 + a3)) * inv;
    size_t row = ((size_t)(b * L + q)) * 512;
    inp[row + 256 + tid] = accum;
    inp[row + tid] = v[((size_t)(b * L + q)) * D + tid];
}

// ---------------- Bidirectional GRU recurrence (operand-swapped MFMA) ---------------
// One block per (dir, batch), 512 threads = 8 waves. Wave w owns gate dims
// jj = 16w..16w+15. h is the A operand (row0 = h_hi, row1 = h_lo), W^T is the B
// operand; C[0][c]/C[1][c] land at col c = lane (lanes 0-15), regs 0/1 — the hp
// triplet arrives directly in the gate lane's own acc registers. Per step:
// MFMA -> gate ALU -> hbuf write -> ONE bar_lds. A = bf16(W) (absmax 0.0039 ok);
// h stays f32-exact via hi/lo rows. Chunked global I/O — zero global ops in steps.
__global__ __launch_bounds__(512, 2) void gru_kernel(
    const float* __restrict__ xp_f, const float* __restrict__ xp_b,
    const float* __restrict__ w_hh_f, const float* __restrict__ w_hh_b,
    const float* __restrict__ b_hh_f, const float* __restrict__ b_hh_b,
    const int* __restrict__ lengths, float* __restrict__ out) {
    const int L = 512, H = 128;
    const int dir = blockIdx.x >> 2;
    const int b = blockIdx.x & 3;
    const float* xp = dir ? xp_b : xp_f;
    const float* w_hh = dir ? w_hh_b : w_hh_f;
    const float* b_hh = dir ? b_hh_b : b_hh_f;
    const int tid = threadIdx.x;
    const int wave = tid >> 6;
    const int lane = tid & 63;
    const int mrow = lane & 15;  // n index of B (gate dim within tile); A row index
    const int quad = lane >> 4;  // k-quad
    const int jj = 16 * wave + lane;  // gate dim for lanes lane<16

    __shared__ __align__(16) short hbuf[2][256];   // [parity][hi 0..127 | lo 128..255]
    __shared__ __align__(16) float xbuf[16 * 384]; // xp chunk stage (24 KB)
    __shared__ __align__(16) float obuf[16 * 128]; // output stage (8 KB)

    // ---- B-fragments (weights): wave w, gate g, B[k][n] = W_hh[g*128+16w+n][k] ----
    short8 wb[3][4];
#pragma unroll
    for (int g = 0; g < 3; g++) {
        int row = g * 128 + 16 * wave + mrow;
#pragma unroll
        for (int kt = 0; kt < 4; kt++) {
            const float* wp = w_hh + (size_t)row * H + kt * 32 + quad * 8;
            float4 w0 = *(const float4*)(wp);
            float4 w1 = *(const float4*)(wp + 4);
            float wv[8] = {w0.x, w0.y, w0.z, w0.w, w1.x, w1.y, w1.z, w1.w};
            short8 hi8;
#pragma unroll
            for (int k = 0; k < 8; k++) hi8[k] = f2bf(wv[k]);
            wb[g][kt] = hi8;
        }
    }
    float br = 0.f, bz = 0.f, bn = 0.f, hcur = 0.f;
    if (lane < 16) {
        br = b_hh[jj];
        bz = b_hh[128 + jj];
        bn = b_hh[256 + jj];
    }

    const int len = lengths[b];
    // pre-zero masked tail: out[b, t, dir*128+k] = 0 for t in [len, L)
    for (int idx = tid; idx < (L - len) * 128; idx += 512) {
        int tt = len + (idx >> 7);
        int kk = idx & 127;
        out[((size_t)(b * L + tt)) * 256 + dir * 128 + kk] = 0.f;
    }
    if (tid < 256) hbuf[0][tid] = 0;

    // staging geometry: 1536 float4 per chunk, 3 per thread
    const int f1 = tid + 512, f2 = tid + 1024;
    const int sA = tid / 96, jA = (tid % 96) * 4;
    const int sB = f1 / 96, jB = (f1 % 96) * 4;
    const int sC = f2 / 96, jC = (f2 % 96) * 4;

    const int nch = (len + 15) >> 4;  // len >= 256 so chunk 0 is full
    float4 r0, r1, r2;
    {
        int tA = dir ? (len - 1 - sA) : sA;
        int tB = dir ? (len - 1 - sB) : sB;
        int tC = dir ? (len - 1 - sC) : sC;
        r0 = *(const float4*)&xp[((size_t)(b * L + tA)) * 384 + jA];
        r1 = *(const float4*)&xp[((size_t)(b * L + tB)) * 384 + jB];
        r2 = *(const float4*)&xp[((size_t)(b * L + tC)) * 384 + jC];
    }
    __syncthreads();

    const int bbase = (mrow & 1) * 128 + quad * 8;  // A-frag index: row0=hi, row1=lo
    int par = 0;

    for (int c = 0; c < nch; c++) {
        const int cnt = min(16, len - c * 16);
        // commit staged regs (vmcnt wait lands here, hidden by a full chunk)
        if (sA < cnt) *(float4*)&xbuf[sA * 384 + jA] = r0;
        if (sB < cnt) *(float4*)&xbuf[sB * 384 + jB] = r1;
        if (sC < cnt) *(float4*)&xbuf[sC * 384 + jC] = r2;
        // flush previous chunk's outputs (always a full 16 rows)
        if (c > 0) {
            int p0 = (c - 1) * 16;
            for (int i = tid; i < 16 * 128; i += 512) {
                int ss = i >> 7, kk = i & 127;
                int tt = dir ? (len - 1 - (p0 + ss)) : (p0 + ss);
                out[((size_t)(b * L + tt)) * 256 + dir * 128 + kk] = obuf[i];
            }
        }
        // prefetch chunk c+1 into registers
        if (c + 1 < nch) {
            int ncnt = min(16, len - (c + 1) * 16);
            int base = (c + 1) * 16;
            if (sA < ncnt) {
                int tt = dir ? (len - 1 - (base + sA)) : (base + sA);
                r0 = *(const float4*)&xp[((size_t)(b * L + tt)) * 384 + jA];
            }
            if (sB < ncnt) {
                int tt = dir ? (len - 1 - (base + sB)) : (base + sB);
                r1 = *(const float4*)&xp[((size_t)(b * L + tt)) * 384 + jB];
            }
            if (sC < ncnt) {
                int tt = dir ? (len - 1 - (base + sC)) : (base + sC);
                r2 = *(const float4*)&xp[((size_t)(b * L + tt)) * 384 + jC];
            }
        }
        bar_lds();  // xbuf visible; prev obuf reads complete
        for (int s = 0; s < cnt; s++) {
            // gate-input LDS reads issued early (latency hidden under MFMA)
            float xr, xz, xn;
            if (lane < 16) {
                xr = xbuf[s * 384 + jj];
                xz = xbuf[s * 384 + 128 + jj];
                xn = xbuf[s * 384 + 256 + jj];
            }
            // A-fragments: rows 0/1 = h_hi/h_lo (rows 2-15 duplicates, ignored in C)
            short8 af[4];
#pragma unroll
            for (int kt = 0; kt < 4; kt++) af[kt] = *(const short8*)&hbuf[par][bbase + kt * 32];
            f32x4 acc[3];
#pragma unroll
            for (int g = 0; g < 3; g++) acc[g] = (f32x4){0.f, 0.f, 0.f, 0.f};
#pragma unroll
            for (int kt = 0; kt < 4; kt++)
#pragma unroll
                for (int g = 0; g < 3; g++)
                    acc[g] = __builtin_amdgcn_mfma_f32_16x16x32_bf16(af[kt], wb[g][kt], acc[g], 0, 0, 0);
            // C col = lane (lanes 0-15 = this wave's gate dims); regs 0/1 = W.h_hi/W.h_lo
            if (lane < 16) {
                float hr = acc[0][0] + acc[0][1] + br;
                float hz = acc[1][0] + acc[1][1] + bz;
                float hh = acc[2][0] + acc[2][1] + bn;
                float r = fast_sigmoid(xr + hr);
                float z = fast_sigmoid(xz + hz);
                float n = fast_tanh(xn + r * hh);
                float hn = (1.f - z) * n + z * hcur;
                hcur = hn;
                short hb = f2bf(hn);
                hbuf[par ^ 1][jj] = hb;
                hbuf[par ^ 1][128 + jj] = f2bf(hn - bf2f(hb));
                obuf[s * 128 + jj] = hn;
            }
            par ^= 1;
            bar_lds();  // hbuf[par] ready for all waves; single barrier per step
        }
    }
    // final flush (last chunk, possibly partial)
    {
        int p0 = (nch - 1) * 16;
        int pcnt = len - p0;
        for (int i = tid; i < pcnt * 128; i += 512) {
            int ss = i >> 7, kk = i & 127;
            int tt = dir ? (len - 1 - (p0 + ss)) : (p0 + ss);
            out[((size_t)(b * L + tt)) * 256 + dir * 128 + kk] = obuf[i];
        }
    }
}

extern "C" void kernel_launch(void* const* d_in, const int* in_sizes, int n_in,
                              void* d_out, int out_size, void* d_ws, size_t ws_size,
                              hipStream_t stream) {
    const int B = 4, L = 512, D = 256, H = 128;
    const int M = B * L;  // 2048

    const float* v      = (const float*)d_in[0];
    const int* lengths  = (const int*)d_in[1];
    // d_in[2] = p_mask (bool) — unused, lengths is equivalent
    const float* own_W  = (const float*)d_in[3];
    const float* own_b  = (const float*)d_in[4];
    const float* comp_W = (const float*)d_in[5];
    const float* comp_b = (const float*)d_in[6];
    const float* v_attn = (const float*)d_in[7];
    const float* gate_W = (const float*)d_in[8];
    const float* gate_b = (const float*)d_in[9];
    const float* w_ih_f = (const float*)d_in[10];
    const float* w_hh_f = (const float*)d_in[11];
    const float* b_ih_f = (const float*)d_in[12];
    const float* b_hh_f = (const float*)d_in[13];
    const float* w_ih_b = (const float*)d_in[14];
    const float* w_hh_b = (const float*)d_in[15];
    const float* b_ih_b = (const float*)d_in[16];
    const float* b_hh_b = (const float*)d_in[17];

    float* ws   = (float*)d_ws;
    float* own  = ws;                       // [2048,128]
    float* comp = own + (size_t)M * H;      // [2048,128]
    float* inp  = comp + (size_t)M * H;     // [2048,512]
    float* gated = inp + (size_t)M * 512;   // [2048,512]
    float* xp_f = gated + (size_t)M * 512;  // [2048,384]
    float* xp_b = xp_f + (size_t)M * 384;   // [2048,384]
    float* out  = (float*)d_out;            // [2048,256]

    // 1: own & comp projections in one launch (tiles 0..1 -> own, 2..3 -> comp)
    gemm_bias<<<dim3(4, M / 64), 256, 0, stream>>>(
        v, own_W, own_b, own, comp_W, comp_b, comp, lengths, M, H, D, 2, 0);
    // 2: attention -> inp = [v, C]
    attn_kernel<<<dim3(B * L), 256, 0, stream>>>(v, lengths, own, comp, v_attn, inp);
    // 3: gate
    gemm_bias<<<dim3(8, M / 64), 256, 0, stream>>>(
        inp, gate_W, gate_b, gated, gate_W, gate_b, gated, lengths, M, 512, 512, 8, 1);
    // 4: input projections for both GRU directions in one launch
    gemm_bias<<<dim3(12, M / 64), 256, 0, stream>>>(
        gated, w_ih_f, b_ih_f, xp_f, w_ih_b, b_ih_b, xp_b, lengths, M, 384, 512, 6, 0);
    // 5: sequential GRU, one block per (dir, batch)
    gru_kernel<<<dim3(8), 512, 0, stream>>>(xp_f, xp_b, w_hh_f, w_hh_b, b_hh_f, b_hh_b, lengths, out);
}